// Round 1
// 86.428 us; speedup vs baseline: 1.0114x; 1.0114x over previous
//
#include <hip/hip_runtime.h>
#include <hip/hip_bf16.h>

// out[i] = x_i @ Q @ x_i, x [1024,2048] fp32 binary, Q [2048,2048] fp32.
// Identity: x^T Q x == x^T Q^T x -> MFMA B-operand (N x K) = row-major Q.
// R14: pipeline restructure. The R12 single-shot block (stage -> one barrier
// -> compute -> die) exposed full staging latency per block (MfmaUtil ~3%).
// Now each block owns KPER=256 of K as FOUR double-buffered BK=64 tiles:
// stage(t+1) is issued BEFORE compute(t), one vmcnt-drain barrier per tile
// (T3 "minimum 2-phase" recipe) -> only the prologue stage is exposed.
// LDS footprint unchanged (2x16KB + 2KB = 34KB, same residency as R12).
// Grid (16,8,8) = 1024 blocks. Swizzle scheme identical in structure:
// LDS slot s of row r holds global chunk s ^ (r&7) -> frag reads 2-way
// banked (free); gload_lds dest stays linear (base + lane*16).

#define B_ROWS 1024
#define N_BITS 2048

#define BM 128
#define BN 128
#define BK 64                    // bf16 per tile row = 128 B = 8 chunks
#define KSPLIT 8
#define KPER (N_BITS / KSPLIT)   // 256
#define NT (KPER / BK)           // 4 pipelined tiles per block
#define NKB (N_BITS / BN)        // 16 n-blocks
#define NPART (NKB * KSPLIT)     // 128 partials per row

typedef __bf16 bf16_t;
typedef __bf16 bf16x8 __attribute__((ext_vector_type(8)));
typedef float f32x4 __attribute__((ext_vector_type(4)));

__device__ __forceinline__ void load16_to_lds(const void* g, void* l) {
  __builtin_amdgcn_global_load_lds(
      (__attribute__((address_space(1))) void*)(g),
      (__attribute__((address_space(3))) void*)(l),
      16, 0, 0);
}

// 8 bits -> 8 bf16 {0.0, 1.0}; explicit per-bit selects (no dynamic local
// array indexing -> no scratch).
__device__ __forceinline__ bf16x8 expand8(unsigned int byte) {
  union { bf16x8 v; unsigned int w[4]; } u;
#pragma unroll
  for (int p = 0; p < 4; ++p) {
    const unsigned int lo = (byte & (1u << (2 * p)))     ? 0x00003F80u : 0u;
    const unsigned int hi = (byte & (1u << (2 * p + 1))) ? 0x3F800000u : 0u;
    u.w[p] = lo | hi;
  }
  return u.v;
}

// prep: fp32 -> bf16 for Q (4M elems) into ws; pack x bits (1 byte / 8 elems).
__global__ __launch_bounds__(256) void prep_kernel(
    const float* __restrict__ x, const float* __restrict__ Q,
    bf16_t* __restrict__ qb, unsigned char* __restrict__ xpack) {
  const int tid = blockIdx.x * 256 + threadIdx.x;
  const int PTH = (B_ROWS * N_BITS) / 8;  // 262144 pack threads
  if (tid < PTH) {
    const float4* s = (const float4*)(x + (size_t)tid * 8);
    float4 v0 = s[0];
    float4 v1 = s[1];
    unsigned int b = 0;
    b |= (v0.x != 0.f) << 0;
    b |= (v0.y != 0.f) << 1;
    b |= (v0.z != 0.f) << 2;
    b |= (v0.w != 0.f) << 3;
    b |= (v1.x != 0.f) << 4;
    b |= (v1.y != 0.f) << 5;
    b |= (v1.z != 0.f) << 6;
    b |= (v1.w != 0.f) << 7;
    xpack[tid] = (unsigned char)b;
  } else {
    const size_t o = (size_t)(tid - PTH) * 8;
    const float4* s = (const float4*)(Q + o);
    float4 v0 = s[0];
    float4 v1 = s[1];
    union { int4 i4; __hip_bfloat16 h[8]; } u;
    u.h[0] = __float2bfloat16(v0.x);
    u.h[1] = __float2bfloat16(v0.y);
    u.h[2] = __float2bfloat16(v0.z);
    u.h[3] = __float2bfloat16(v0.w);
    u.h[4] = __float2bfloat16(v1.x);
    u.h[5] = __float2bfloat16(v1.y);
    u.h[6] = __float2bfloat16(v1.z);
    u.h[7] = __float2bfloat16(v1.w);
    ((int4*)(qb + o))[0] = u.i4;
  }
}

// GEMM S = bits(X) @ Qb^T (16x16x32 frags) + bit-masked row-dot -> partials.
// 4 waves split M (32 rows x 128 cols each, acc 2x8). Double-buffered K-loop.
__global__ __launch_bounds__(256) void qubo_kernel(
    const bf16_t* __restrict__ Qb, const unsigned char* __restrict__ xpack,
    float* __restrict__ partial) {
  __shared__ bf16_t ldsB[2][BN * BK];          // 2 x 16 KB
  __shared__ unsigned long long mbits[BM * 2]; // 2 KB: 128 n-bits per row

  const int tid  = threadIdx.x;
  const int lane = tid & 63;
  const int wave = tid >> 6;     // 0..3 -> owns rows [wave*32, wave*32+32)
  const int lrow = lane & 15;
  const int quad = lane >> 4;

  const int m0    = blockIdx.y * BM;
  const int n0    = blockIdx.x * BN;
  const int kbase = blockIdx.z * KPER;
  const int nkid  = blockIdx.x * KSPLIT + blockIdx.z;  // 0..127

  // Tile staging: 128 rows x 8 chunks (16B) = 4 per thread, 4 row-passes.
  // LDS dest linear in lane (byte off within pass = lane*16, as
  // global_load_lds requires). GLOBAL chunk XOR-swizzled: LDS slot s of
  // row r holds global chunk s ^ (r&7) -> frag reads 2-way banked (free).
  const int srow = tid >> 3;        // 0..31
  const int slot = tid & 7;         // 0..7
  const int gch  = slot ^ (srow & 7);  // r&7 == srow&7 for every pass

  // Prologue: stage tile 0 into buf 0.
#pragma unroll
  for (int p = 0; p < 4; ++p) {
    const int r = p * 32 + srow;
    load16_to_lds(Qb + (size_t)(n0 + r) * N_BITS + kbase + gch * 8,
                  &ldsB[0][r * BK + slot * 8]);
  }
  // mask bits (n0-slice): 128 rows x 16 B by waves 0-1, same vmcnt window.
  if (wave < 2) {
    load16_to_lds(xpack + (size_t)(m0 + tid) * (N_BITS / 8) + (n0 >> 3),
                  (void*)(mbits + tid * 2));
  }

  // A bits (full KPER=256-bit k-slice): 32 B per owned row, straight to
  // registers — no barrier dependency. 4 lanes/row redundancy is L1-broadcast.
  unsigned long long abits[2][NT];
#pragma unroll
  for (int mi = 0; mi < 2; ++mi) {
    const int row = m0 + wave * 32 + mi * 16 + lrow;
    const ulonglong2* ap =
        (const ulonglong2*)(xpack + (size_t)row * (N_BITS / 8) +
                            (kbase >> 3));
    ulonglong2 v0 = ap[0];
    ulonglong2 v1 = ap[1];
    abits[mi][0] = v0.x;
    abits[mi][1] = v0.y;
    abits[mi][2] = v1.x;
    abits[mi][3] = v1.y;
  }

  f32x4 acc[2][8];
#pragma unroll
  for (int i = 0; i < 2; ++i)
#pragma unroll
    for (int j = 0; j < 8; ++j) acc[i][j] = (f32x4){0.f, 0.f, 0.f, 0.f};

  __syncthreads();   // drains prologue staging (tile 0 + mask)

  // Pipelined K-loop: issue stage(t+1) BEFORE compute(t); one barrier/tile.
#pragma unroll
  for (int t = 0; t < NT; ++t) {
    if (t + 1 < NT) {
      const int kb = kbase + (t + 1) * BK;
#pragma unroll
      for (int p = 0; p < 4; ++p) {
        const int r = p * 32 + srow;
        load16_to_lds(Qb + (size_t)(n0 + r) * N_BITS + kb + gch * 8,
                      &ldsB[(t + 1) & 1][r * BK + slot * 8]);
      }
    }
#pragma unroll
    for (int ks = 0; ks < 2; ++ks) {
      const int c  = ks * 4 + quad;            // chunk 0..7 within tile
      const int ch = (c ^ (lrow & 7)) * 8;     // un-swizzle
      bf16x8 b[8], a[2];
#pragma unroll
      for (int ni = 0; ni < 8; ++ni)
        b[ni] = *(const bf16x8*)&ldsB[t & 1][(ni * 16 + lrow) * BK + ch];
#pragma unroll
      for (int mi = 0; mi < 2; ++mi) {
        // word index t is compile-time (full unroll): no scratch.
        const unsigned int byte =
            (unsigned int)((abits[mi][t] >> ((ks * 4 + quad) * 8)) & 0xFFu);
        a[mi] = expand8(byte);
      }
#pragma unroll
      for (int mi = 0; mi < 2; ++mi)
#pragma unroll
        for (int ni = 0; ni < 8; ++ni)
          acc[mi][ni] = __builtin_amdgcn_mfma_f32_16x16x32_bf16(
              a[mi], b[ni], acc[mi][ni], 0, 0, 0);
    }
    if (t + 1 < NT) __syncthreads();  // stage(t+1) done; buf(t) free to reuse
  }

  // Epilogue (R11-verified). 16x16 C/D: col = lane&15, row = quad*4 + reg.
  // Bit-mask from LDS (broadcast), cndmask-adds, 16-lane shuffle reduce, one
  // plain store per (row, nkid). No atomics, no fences.
#pragma unroll
  for (int mi = 0; mi < 2; ++mi) {
#pragma unroll
    for (int r = 0; r < 4; ++r) {
      const int rloc = wave * 32 + mi * 16 + quad * 4 + r;
      const unsigned long long w0 = mbits[rloc * 2];      // cols 0..63
      const unsigned long long w1 = mbits[rloc * 2 + 1];  // cols 64..127
      float s = 0.f;
#pragma unroll
      for (int ni = 0; ni < 4; ++ni)
        s += ((w0 >> (ni * 16 + lrow)) & 1ull) ? acc[mi][ni][r] : 0.f;
#pragma unroll
      for (int ni = 4; ni < 8; ++ni)
        s += ((w1 >> ((ni - 4) * 16 + lrow)) & 1ull) ? acc[mi][ni][r] : 0.f;
#pragma unroll
      for (int off = 1; off < 16; off <<= 1)
        s += __shfl_xor(s, off, 64);
      if (lrow == 0)
        partial[(size_t)(m0 + rloc) * NPART + nkid] = s;
    }
  }
}

// reduce: out[row] = sum of 128 partials. One 2-wave block per row, coalesced.
__global__ __launch_bounds__(128) void reduce_kernel(
    const float* __restrict__ partial, float* __restrict__ out) {
  const int row = blockIdx.x;
  const int tid = threadIdx.x;
  float v = partial[(size_t)row * NPART + tid];
#pragma unroll
  for (int off = 1; off < 64; off <<= 1)
    v += __shfl_xor(v, off, 64);
  __shared__ float wsum[2];
  if ((tid & 63) == 0) wsum[tid >> 6] = v;
  __syncthreads();
  if (tid == 0) out[row] = wsum[0] + wsum[1];
}

extern "C" void kernel_launch(void* const* d_in, const int* in_sizes, int n_in,
                              void* d_out, int out_size, void* d_ws, size_t ws_size,
                              hipStream_t stream) {
  const float* x = (const float*)d_in[0];
  const float* Q = (const float*)d_in[1];
  float* out = (float*)d_out;

  bf16_t* qb = (bf16_t*)d_ws;                                                // 8 MB @ 0
  unsigned char* xpack = (unsigned char*)((char*)d_ws + ((size_t)8 << 20));  // 256 KB @ 8M
  float* partial = (float*)((char*)d_ws + ((size_t)9 << 20));                // 512 KB @ 9M

  // 262144 pack threads + 524288 Q threads = 786432 = 3072 blocks
  prep_kernel<<<3072, 256, 0, stream>>>(x, Q, qb, xpack);

  dim3 grid(NKB, B_ROWS / BM, KSPLIT);  // (16, 8, 8) = 1024 blocks
  qubo_kernel<<<grid, dim3(256), 0, stream>>>(qb, xpack, partial);

  reduce_kernel<<<B_ROWS, 128, 0, stream>>>(partial, out);
}